// Round 3
// baseline (300.861 us; speedup 1.0000x reference)
//
#include <hip/hip_runtime.h>
#include <hip/hip_bf16.h>
#include <stdint.h>

typedef short bf16x8 __attribute__((ext_vector_type(8)));
typedef float f32x4  __attribute__((ext_vector_type(4)));
typedef unsigned short u16;
typedef unsigned int   u32;

#define BATCH 4
#define PTOT  4096   // H*W
#define CINT  128    // inter channels
// (1/sqrt(128)) * log2(e): fold QK scale + exp2 base change into theta
#define QK_SCALE 0.12751744f

__device__ __forceinline__ u32 pk_bf16(float a, float b) {
  u32 r;
  asm("v_cvt_pk_bf16_f32 %0, %1, %2" : "=v"(r) : "v"(a), "v"(b));
  return r;
}
__device__ __forceinline__ u16 f2bf(float x) { return (u16)pk_bf16(x, x); }
__device__ __forceinline__ float bf2f(u16 v) { return __uint_as_float(((u32)v) << 16); }

__device__ __forceinline__ f32x4 mfma16(bf16x8 a, bf16x8 b, f32x4 c) {
  return __builtin_amdgcn_mfma_f32_16x16x32_bf16(a, b, c, 0, 0, 0);
}

// ---------------- all-weights fp32 -> bf16 (one launch) ----------------
// dst layout (u16 elems): Wt[0,32768) Wp[32768,98304) Wg[98304,163840) Wo[163840,196608)
__global__ void k_cvt_all(const float* __restrict__ Wt, const float* __restrict__ Wp,
                          const float* __restrict__ Wg, const float* __restrict__ Wo,
                          u16* __restrict__ dst) {
  int i = (blockIdx.x * 256 + threadIdx.x) * 4;
  const float* s; int off;
  if (i < 32768)       { s = Wt; off = i; }
  else if (i < 98304)  { s = Wp; off = i - 32768; }
  else if (i < 163840) { s = Wg; off = i - 98304; }
  else                 { s = Wo; off = i - 163840; }
  float4 v = *(const float4*)(s + off);
  *(uint2*)(dst + i) = make_uint2(pk_bf16(v.x, v.y), pk_bf16(v.z, v.w));
}

// ---------------- theta projection -> pixel-major [B][p][c'] ----------------
__global__ void k_proj_pix(const float* __restrict__ X, const u16* __restrict__ W,
                           const float* __restrict__ bias, u16* __restrict__ O,
                           int Cin, float scale) {
  const int b = blockIdx.y, p0 = blockIdx.x * 64;
  const int t = threadIdx.x, lane = t & 63, w = t >> 6;
  const int m_ = lane & 15, h = lane >> 4;
  __shared__ __align__(16) u16 At[64][40];
  __shared__ __align__(16) u16 Wl[128][40];
  const float* xb = X + (size_t)b * Cin * PTOT;
  f32x4 acc[4][2];
#pragma unroll
  for (int i = 0; i < 4; i++) { acc[i][0] = (f32x4)0.0f; acc[i][1] = (f32x4)0.0f; }
  const int p = t & 63, cg = t >> 6;
  const int wrow = t >> 1, whalf = t & 1;
  for (int k0 = 0; k0 < Cin; k0 += 32) {
    __syncthreads();
    {
      const float* sx = xb + (size_t)(k0 + 8 * cg) * PTOT + p0 + p;
      float v0 = sx[0],        v1 = sx[PTOT],   v2 = sx[2*PTOT], v3 = sx[3*PTOT];
      float v4 = sx[4*PTOT],   v5 = sx[5*PTOT], v6 = sx[6*PTOT], v7 = sx[7*PTOT];
      *(uint2*)&At[p][8*cg]     = make_uint2(pk_bf16(v0,v1), pk_bf16(v2,v3));
      *(uint2*)&At[p][8*cg + 4] = make_uint2(pk_bf16(v4,v5), pk_bf16(v6,v7));
    }
    {
      const u16* sw = W + (size_t)wrow * Cin + k0 + whalf * 16;
      uint4 a = *(const uint4*)sw, c = *(const uint4*)(sw + 8);
      *(uint4*)&Wl[wrow][whalf*16]     = a;
      *(uint4*)&Wl[wrow][whalf*16 + 8] = c;
    }
    __syncthreads();
    bf16x8 bf0 = *(const bf16x8*)&Wl[w*32 + m_][8*h];
    bf16x8 bf1 = *(const bf16x8*)&Wl[w*32 + 16 + m_][8*h];
#pragma unroll
    for (int mb = 0; mb < 4; mb++) {
      bf16x8 af = *(const bf16x8*)&At[mb*16 + m_][8*h];
      acc[mb][0] = mfma16(af, bf0, acc[mb][0]);
      acc[mb][1] = mfma16(af, bf1, acc[mb][1]);
    }
  }
  u16* ob = O + (size_t)b * PTOT * CINT;
#pragma unroll
  for (int mb = 0; mb < 4; mb++)
#pragma unroll
    for (int nb = 0; nb < 2; nb++) {
      int c = w*32 + nb*16 + m_;
      float bv = bias[c];
#pragma unroll
      for (int r = 0; r < 4; r++) {
        int pp = p0 + mb*16 + 4*h + r;
        ob[(size_t)pp * CINT + c] = f2bf((acc[mb][nb][r] + bv) * scale);
      }
    }
}

// ---------------- fused reference projections: phi (pixel-major) + g (channel-major) ----------------
__global__ void k_proj_ref(const float* __restrict__ X, const u16* __restrict__ Wp,
                           const u16* __restrict__ Wg, const float* __restrict__ bp,
                           const float* __restrict__ bg, u16* __restrict__ PH,
                           u16* __restrict__ Gm) {
  const int Cin = 512;
  const int b = blockIdx.y, p0 = blockIdx.x * 64;
  const int t = threadIdx.x, lane = t & 63, w = t >> 6;
  const int m_ = lane & 15, h = lane >> 4;
  __shared__ __align__(16) u16 Bt[64][40];
  __shared__ __align__(16) u16 Wpl[128][40];
  __shared__ __align__(16) u16 Wgl[128][40];
  const float* xb = X + (size_t)b * Cin * PTOT;
  f32x4 accp[4][2];  // PH: rows p, cols c'
  f32x4 accg[2][4];  // G : rows c', cols p
#pragma unroll
  for (int i = 0; i < 4; i++) { accp[i][0] = (f32x4)0.0f; accp[i][1] = (f32x4)0.0f; }
#pragma unroll
  for (int i = 0; i < 2; i++)
#pragma unroll
    for (int j = 0; j < 4; j++) accg[i][j] = (f32x4)0.0f;
  const int p = t & 63, cg = t >> 6;
  const int wrow = t >> 1, whalf = t & 1;
  for (int k0 = 0; k0 < Cin; k0 += 32) {
    __syncthreads();
    {
      const float* sx = xb + (size_t)(k0 + 8 * cg) * PTOT + p0 + p;
      float v0 = sx[0],        v1 = sx[PTOT],   v2 = sx[2*PTOT], v3 = sx[3*PTOT];
      float v4 = sx[4*PTOT],   v5 = sx[5*PTOT], v6 = sx[6*PTOT], v7 = sx[7*PTOT];
      *(uint2*)&Bt[p][8*cg]     = make_uint2(pk_bf16(v0,v1), pk_bf16(v2,v3));
      *(uint2*)&Bt[p][8*cg + 4] = make_uint2(pk_bf16(v4,v5), pk_bf16(v6,v7));
    }
    {
      const u16* sw = Wp + (size_t)wrow * Cin + k0 + whalf * 16;
      *(uint4*)&Wpl[wrow][whalf*16]     = *(const uint4*)sw;
      *(uint4*)&Wpl[wrow][whalf*16 + 8] = *(const uint4*)(sw + 8);
      const u16* sg = Wg + (size_t)wrow * Cin + k0 + whalf * 16;
      *(uint4*)&Wgl[wrow][whalf*16]     = *(const uint4*)sg;
      *(uint4*)&Wgl[wrow][whalf*16 + 8] = *(const uint4*)(sg + 8);
    }
    __syncthreads();
    {
      bf16x8 bf0 = *(const bf16x8*)&Wpl[w*32 + m_][8*h];
      bf16x8 bf1 = *(const bf16x8*)&Wpl[w*32 + 16 + m_][8*h];
#pragma unroll
      for (int mb = 0; mb < 4; mb++) {
        bf16x8 af = *(const bf16x8*)&Bt[mb*16 + m_][8*h];
        accp[mb][0] = mfma16(af, bf0, accp[mb][0]);
        accp[mb][1] = mfma16(af, bf1, accp[mb][1]);
      }
    }
    {
      bf16x8 bfr[4];
#pragma unroll
      for (int nb = 0; nb < 4; nb++) bfr[nb] = *(const bf16x8*)&Bt[nb*16 + m_][8*h];
#pragma unroll
      for (int mb = 0; mb < 2; mb++) {
        bf16x8 af = *(const bf16x8*)&Wgl[w*32 + mb*16 + m_][8*h];
#pragma unroll
        for (int nb = 0; nb < 4; nb++) accg[mb][nb] = mfma16(af, bfr[nb], accg[mb][nb]);
      }
    }
  }
  {
    u16* ob = PH + (size_t)b * PTOT * CINT;
#pragma unroll
    for (int mb = 0; mb < 4; mb++)
#pragma unroll
      for (int nb = 0; nb < 2; nb++) {
        int c = w*32 + nb*16 + m_;
        float bv = bp[c];
#pragma unroll
        for (int r = 0; r < 4; r++) {
          int pp = p0 + mb*16 + 4*h + r;
          ob[(size_t)pp * CINT + c] = f2bf(accp[mb][nb][r] + bv);
        }
      }
  }
  {
    u16* ob = Gm + (size_t)b * CINT * PTOT;
#pragma unroll
    for (int mb = 0; mb < 2; mb++)
#pragma unroll
      for (int nb = 0; nb < 4; nb++) {
        int pidx = p0 + nb*16 + m_;
#pragma unroll
        for (int r = 0; r < 4; r++) {
          int c = w*32 + mb*16 + 4*h + r;
          ob[(size_t)c * PTOT + pidx] = f2bf(accg[mb][nb][r] + bg[c]);
        }
      }
  }
}

// ---------------- flash attention (T14 reg-prefetch, T13 defer-max, T5 setprio) ----------------
// LDS: XOR-swizzled linear tiles, exactly 40 KiB -> 4 blocks/CU.
// SPLIT>1: partial sums U (bf16, unnormalized) + ML (m,l fp32); SPLIT==1: Y direct.
template<int SPLIT>
__global__ __launch_bounds__(256, 4)
void k_attn(const u16* __restrict__ TH, const u16* __restrict__ PH,
            const u16* __restrict__ G, u16* __restrict__ U,
            float* __restrict__ ML, u16* __restrict__ Y) {
  constexpr int LSPLIT = (SPLIT == 4) ? 2 : ((SPLIT == 2) ? 1 : 0);
  constexpr int NITER = 64 >> LSPLIT;
  const int total = 64 * BATCH * SPLIT;
  // XCD-bijective swizzle: each XCD gets contiguous gid range -> same-(b,z) KV panel per XCD L2
  const int did = blockIdx.x;
  const int gid = (did & 7) * (total >> 3) + (did >> 3);
  const int qb = gid & 63, grp = gid >> 6;
  const int z = grp & (SPLIT - 1), b = grp >> LSPLIT;
  const int t = threadIdx.x, lane = t & 63, w = t >> 6;
  const int m_ = lane & 15, h = lane >> 4;
  __shared__ __align__(16) u16 Kl[64 * 128];   // phi rows [k][c], swizzled
  __shared__ __align__(16) u16 Vl[128 * 64];   // g rows [c'][k], swizzled
  __shared__ __align__(16) u16 Pl[4 * 16 * 64];// per-wave P [q][k], swizzled
  const u16* thb = TH + (size_t)b * PTOT * CINT;
  const u16* phb = PH + (size_t)b * PTOT * CINT;
  const u16* gb  = G  + (size_t)b * CINT * PTOT;
  const int q = qb * 64 + w * 16 + m_;
  bf16x8 qf[4];
  {
    const u16* qr = thb + (size_t)q * CINT + 8*h;
    qf[0] = *(const bf16x8*)(qr);
    qf[1] = *(const bf16x8*)(qr + 32);
    qf[2] = *(const bf16x8*)(qr + 64);
    qf[3] = *(const bf16x8*)(qr + 96);
  }
  f32x4 yacc[8];
#pragma unroll
  for (int i = 0; i < 8; i++) yacc[i] = (f32x4)0.0f;
  float mrun = -3.0e38f, lrun = 0.0f;
  const int krow = t >> 4, kch = t & 15;   // K stage: rows krow+16i, col kch*8
  const int vrow = t >> 3, vch = t & 7;    // V stage: rows vrow+32i, col vch*8
  const int it0 = z * NITER;
  uint4 rk[4], rv[4];
  auto LOADT = [&](int it) {
    const u16* ps = phb + (size_t)(it * 64 + krow) * CINT + kch * 8;
#pragma unroll
    for (int i = 0; i < 4; i++) rk[i] = *(const uint4*)(ps + (size_t)(16 * i) * CINT);
    const u16* vs = gb + (size_t)vrow * PTOT + it * 64 + vch * 8;
#pragma unroll
    for (int i = 0; i < 4; i++) rv[i] = *(const uint4*)(vs + (size_t)(32 * i) * PTOT);
  };
  LOADT(it0);
  for (int it = it0; it < it0 + NITER; ++it) {
    __syncthreads();   // previous compute done reading LDS
#pragma unroll
    for (int i = 0; i < 4; i++) {
      int r = krow + 16 * i;
      *(uint4*)&Kl[r * 128 + ((kch * 8) ^ ((r & 7) << 3))] = rk[i];
    }
#pragma unroll
    for (int i = 0; i < 4; i++) {
      int r = vrow + 32 * i;
      *(uint4*)&Vl[r * 64 + ((vch * 8) ^ ((r & 7) << 3))] = rv[i];
    }
    __syncthreads();   // tile visible
    if (it + 1 < it0 + NITER) LOADT(it + 1);   // prefetch in flight under compute
    // ---- QK: S^T[k][q] ----
    f32x4 sa[4];
#pragma unroll
    for (int i = 0; i < 4; i++) sa[i] = (f32x4)0.0f;
    __builtin_amdgcn_s_setprio(1);
#pragma unroll
    for (int ks = 0; ks < 4; ks++) {
#pragma unroll
      for (int mb = 0; mb < 4; mb++) {
        int r = mb * 16 + m_;
        bf16x8 af = *(const bf16x8*)&Kl[r * 128 + ((ks * 32 + 8 * h) ^ ((r & 7) << 3))];
        sa[mb] = mfma16(af, qf[ks], sa[mb]);
      }
    }
    __builtin_amdgcn_s_setprio(0);
    // ---- online softmax over k (defer-max) ----
    float tmax = fmaxf(fmaxf(fmaxf(sa[0][0], sa[0][1]), fmaxf(sa[0][2], sa[0][3])),
                       fmaxf(fmaxf(sa[1][0], sa[1][1]), fmaxf(sa[1][2], sa[1][3])));
    float tmx2 = fmaxf(fmaxf(fmaxf(sa[2][0], sa[2][1]), fmaxf(sa[2][2], sa[2][3])),
                       fmaxf(fmaxf(sa[3][0], sa[3][1]), fmaxf(sa[3][2], sa[3][3])));
    tmax = fmaxf(tmax, tmx2);
    tmax = fmaxf(tmax, __shfl_xor(tmax, 16));
    tmax = fmaxf(tmax, __shfl_xor(tmax, 32));
    if (!__all(tmax <= mrun + 8.0f)) {
      float mnew = fmaxf(mrun, tmax);
      float f = exp2f(mrun - mnew);
      mrun = mnew;
      lrun *= f;
#pragma unroll
      for (int i = 0; i < 8; i++) yacc[i] *= f;
    }
    float ts = 0.0f;
#pragma unroll
    for (int mb = 0; mb < 4; mb++) {
      float e0 = exp2f(sa[mb][0] - mrun);
      float e1 = exp2f(sa[mb][1] - mrun);
      float e2 = exp2f(sa[mb][2] - mrun);
      float e3 = exp2f(sa[mb][3] - mrun);
      ts += (e0 + e1) + (e2 + e3);
      *(uint2*)&Pl[w * 1024 + m_ * 64 + ((mb * 16 + 4 * h) ^ ((m_ & 7) << 3))] =
          make_uint2(pk_bf16(e0, e1), pk_bf16(e2, e3));
    }
    ts += __shfl_xor(ts, 16);
    ts += __shfl_xor(ts, 32);
    lrun += ts;
    asm volatile("s_waitcnt lgkmcnt(0)" ::: "memory");  // wave-private P ready (vmcnt untouched)
    __builtin_amdgcn_sched_barrier(0);
    // ---- PV: y^T[c'][q] += g[c'][k] * P[q][k] ----
    __builtin_amdgcn_s_setprio(1);
#pragma unroll
    for (int ks = 0; ks < 2; ks++) {
      bf16x8 pb = *(const bf16x8*)&Pl[w * 1024 + m_ * 64 + ((ks * 32 + 8 * h) ^ ((m_ & 7) << 3))];
#pragma unroll
      for (int mb = 0; mb < 8; mb++) {
        int r = mb * 16 + m_;
        bf16x8 av = *(const bf16x8*)&Vl[r * 64 + ((ks * 32 + 8 * h) ^ ((r & 7) << 3))];
        yacc[mb] = mfma16(av, pb, yacc[mb]);
      }
    }
    __builtin_amdgcn_s_setprio(0);
  }
  if constexpr (SPLIT > 1) {
    u16* ub = U + (((size_t)(z * BATCH + b)) * PTOT + q) * CINT;
#pragma unroll
    for (int mb = 0; mb < 8; mb++) {
      f32x4 v = yacc[mb];
      *(uint2*)(ub + mb * 16 + 4 * h) = make_uint2(pk_bf16(v[0], v[1]), pk_bf16(v[2], v[3]));
    }
    if (h == 0) {
      float* mlb = ML + ((size_t)(z * BATCH + b) * PTOT + q) * 2;
      mlb[0] = mrun; mlb[1] = lrun;
    }
  } else {
    float inv = 1.0f / lrun;
    u16* yb = Y + ((size_t)b * PTOT + q) * CINT;
#pragma unroll
    for (int mb = 0; mb < 8; mb++) {
      f32x4 v = yacc[mb];
      *(uint2*)(yb + mb * 16 + 4 * h) =
          make_uint2(pk_bf16(v[0] * inv, v[1] * inv), pk_bf16(v[2] * inv, v[3] * inv));
    }
  }
}

// ---------------- combine SPLIT partials ----------------
template<int SPLIT>
__global__ void k_combine(const u16* __restrict__ U, const float* __restrict__ ML,
                          u16* __restrict__ Y) {
  int tid = blockIdx.x * 256 + threadIdx.x;     // 4*4096*16 threads
  int c8 = (tid & 15) * 8;
  int q  = (tid >> 4) & (PTOT - 1);
  int b  = tid >> 16;
  float ms[SPLIT], ls[SPLIT];
  float M = -3.0e38f;
#pragma unroll
  for (int s = 0; s < SPLIT; s++) {
    const float* p = ML + ((size_t)(s * BATCH + b) * PTOT + q) * 2;
    ms[s] = p[0]; ls[s] = p[1];
    M = fmaxf(M, ms[s]);
  }
  float L = 0.0f;
#pragma unroll
  for (int s = 0; s < SPLIT; s++) { ms[s] = exp2f(ms[s] - M); L += ls[s] * ms[s]; }
  float inv = 1.0f / L;
  float acc[8];
#pragma unroll
  for (int j = 0; j < 8; j++) acc[j] = 0.0f;
#pragma unroll
  for (int s = 0; s < SPLIT; s++) {
    const u16* up = U + ((size_t)(s * BATCH + b) * PTOT + q) * CINT + c8;
    uint4 v = *(const uint4*)up;
    float f = ms[s];
    acc[0] += bf2f((u16)(v.x & 0xffff)) * f;  acc[1] += bf2f((u16)(v.x >> 16)) * f;
    acc[2] += bf2f((u16)(v.y & 0xffff)) * f;  acc[3] += bf2f((u16)(v.y >> 16)) * f;
    acc[4] += bf2f((u16)(v.z & 0xffff)) * f;  acc[5] += bf2f((u16)(v.z >> 16)) * f;
    acc[6] += bf2f((u16)(v.w & 0xffff)) * f;  acc[7] += bf2f((u16)(v.w >> 16)) * f;
  }
  uint4 o;
  o.x = pk_bf16(acc[0] * inv, acc[1] * inv);
  o.y = pk_bf16(acc[2] * inv, acc[3] * inv);
  o.z = pk_bf16(acc[4] * inv, acc[5] * inv);
  o.w = pk_bf16(acc[6] * inv, acc[7] * inv);
  *(uint4*)(Y + ((size_t)b * PTOT + q) * CINT + c8) = o;
}

// ---------------- output projection + residual ----------------
__global__ void k_outproj(const float* __restrict__ Q, const u16* __restrict__ Wo,
                          const float* __restrict__ bo, const u16* __restrict__ Y,
                          float* __restrict__ O) {
  const int p0 = blockIdx.x * 64, chh = blockIdx.y, b = blockIdx.z;
  const int t = threadIdx.x, lane = t & 63, w = t >> 6;
  const int m_ = lane & 15, h = lane >> 4;
  __shared__ __align__(16) u16 Wl[128][136];
  __shared__ __align__(16) u16 Yl[64][136];
  {
    int row = t >> 1, cc = t & 1;
    const u16* src = Wo + (size_t)(chh*128 + row) * CINT + cc*64;
#pragma unroll
    for (int i = 0; i < 8; i++)
      *(uint4*)&Wl[row][cc*64 + i*8] = *(const uint4*)(src + i*8);
  }
  {
    int row = t >> 2, cc = t & 3;
    const u16* src = Y + ((size_t)b * PTOT + p0 + row) * CINT + cc*32;
#pragma unroll
    for (int i = 0; i < 4; i++)
      *(uint4*)&Yl[row][cc*32 + i*8] = *(const uint4*)(src + i*8);
  }
  __syncthreads();
  f32x4 acc[2][4];
#pragma unroll
  for (int i = 0; i < 2; i++)
#pragma unroll
    for (int j = 0; j < 4; j++) acc[i][j] = (f32x4)0.0f;
#pragma unroll
  for (int ks = 0; ks < 4; ks++) {
    bf16x8 bfr[4];
#pragma unroll
    for (int nb = 0; nb < 4; nb++) bfr[nb] = *(const bf16x8*)&Yl[nb*16 + m_][ks*32 + 8*h];
#pragma unroll
    for (int mb = 0; mb < 2; mb++) {
      bf16x8 af = *(const bf16x8*)&Wl[w*32 + mb*16 + m_][ks*32 + 8*h];
#pragma unroll
      for (int nb = 0; nb < 4; nb++) acc[mb][nb] = mfma16(af, bfr[nb], acc[mb][nb]);
    }
  }
  const size_t cob = (size_t)b * 256 + (size_t)chh * 128;
#pragma unroll
  for (int mb = 0; mb < 2; mb++)
#pragma unroll
    for (int nb = 0; nb < 4; nb++) {
      int pidx = p0 + nb*16 + m_;
#pragma unroll
      for (int r = 0; r < 4; r++) {
        int co = w*32 + mb*16 + 4*h + r;
        size_t idx = (cob + co) * PTOT + pidx;
        O[idx] = Q[idx] + acc[mb][nb][r] + bo[chh*128 + co];
      }
    }
}

extern "C" void kernel_launch(void* const* d_in, const int* in_sizes, int n_in,
                              void* d_out, int out_size, void* d_ws, size_t ws_size,
                              hipStream_t stream) {
  const float* q_in = (const float*)d_in[0];
  const float* ref  = (const float*)d_in[1];
  const float* Wg   = (const float*)d_in[2];
  const float* bg   = (const float*)d_in[3];
  const float* Wt   = (const float*)d_in[4];
  const float* bt   = (const float*)d_in[5];
  const float* Wp   = (const float*)d_in[6];
  const float* bp   = (const float*)d_in[7];
  const float* Wo   = (const float*)d_in[8];
  const float* bo   = (const float*)d_in[9];
  float* out = (float*)d_out;
  char* ws = (char*)d_ws;

  // workspace layout (bytes)
  u16* WB  = (u16*)ws;               // weights bf16: Wt@0 Wp@32768 Wg@98304 Wo@163840 (u16 elems)
  u16* WtB = WB;
  u16* WpB = WB + 32768;
  u16* WgB = WB + 98304;
  u16* WoB = WB + 163840;
  u16* TH  = (u16*)(ws + 393216);    // 4 MiB
  u16* PH  = (u16*)(ws + 4587520);   // 4 MiB
  u16* G   = (u16*)(ws + 8781824);   // 4 MiB
  u16* U   = (u16*)(ws + 12976128);  // SPLIT * 4 MiB (bf16 partials)
  const size_t NEED4 = 12976128 + 16777216 + 524288;  // 30,277,632
  const size_t NEED2 = 12976128 +  8388608 + 262144;  // 21,626,880
  int split = (ws_size >= NEED4) ? 4 : (ws_size >= NEED2) ? 2 : 1;
  float* ML = (float*)(ws + 12976128 + (size_t)split * 4194304);
  // Y reuses TH (theta dead after k_attn) for split>1; separate slot for split==1
  u16* Y = (split > 1) ? TH : (u16*)(ws + 12976128);

  k_cvt_all<<<192, 256, 0, stream>>>(Wt, Wp, Wg, Wo, WB);

  dim3 gp(64, BATCH);
  k_proj_pix<<<gp, 256, 0, stream>>>(q_in, WtB, bt, TH, 256, QK_SCALE);
  k_proj_ref<<<gp, 256, 0, stream>>>(ref, WpB, WgB, bp, bg, PH, G);

  if (split == 4) {
    k_attn<4><<<1024, 256, 0, stream>>>(TH, PH, G, U, ML, Y);
    k_combine<4><<<1024, 256, 0, stream>>>(U, ML, Y);
  } else if (split == 2) {
    k_attn<2><<<512, 256, 0, stream>>>(TH, PH, G, U, ML, Y);
    k_combine<2><<<1024, 256, 0, stream>>>(U, ML, Y);
  } else {
    k_attn<1><<<256, 256, 0, stream>>>(TH, PH, G, U, ML, Y);
  }

  dim3 go(64, 2, BATCH);
  k_outproj<<<go, 256, 0, stream>>>(q_in, WoB, bo, Y, out);
}

// Round 4
// 193.678 us; speedup vs baseline: 1.5534x; 1.5534x over previous
//
#include <hip/hip_runtime.h>
#include <hip/hip_bf16.h>
#include <stdint.h>

typedef short bf16x8 __attribute__((ext_vector_type(8)));
typedef float f32x4  __attribute__((ext_vector_type(4)));
typedef float f32x16 __attribute__((ext_vector_type(16)));
typedef unsigned short u16;
typedef unsigned int   u32;

#define BATCH 4
#define PTOT  4096   // H*W
#define CINT  128    // inter channels
// (1/sqrt(128)) * log2(e): fold QK scale + exp2 base change into theta
#define QK_SCALE 0.12751744f

__device__ __forceinline__ u32 pk_bf16(float a, float b) {
  u32 r;
  asm("v_cvt_pk_bf16_f32 %0, %1, %2" : "=v"(r) : "v"(a), "v"(b));
  return r;
}
__device__ __forceinline__ u16 f2bf(float x) { return (u16)pk_bf16(x, x); }
__device__ __forceinline__ float bf2f(u16 v) { return __uint_as_float(((u32)v) << 16); }

__device__ __forceinline__ f32x4 mfma16(bf16x8 a, bf16x8 b, f32x4 c) {
  return __builtin_amdgcn_mfma_f32_16x16x32_bf16(a, b, c, 0, 0, 0);
}
__device__ __forceinline__ f32x16 mfma32(bf16x8 a, bf16x8 b, f32x16 c) {
  return __builtin_amdgcn_mfma_f32_32x32x16_bf16(a, b, c, 0, 0, 0);
}
__device__ __forceinline__ void gload16(const u16* g, u16* l) {
  __builtin_amdgcn_global_load_lds((const __attribute__((address_space(1))) u32*)g,
                                   (__attribute__((address_space(3))) u32*)l, 16, 0, 0);
}
// Build a 32x32 MFMA A-operand fragment of P (8 consecutive k per lane-half)
// from 8 softmax values e[crow order] via 4 cvt_pk + 2 permlane32_swap.
__device__ __forceinline__ bf16x8 mkfrag(float a0, float a1, float a2, float a3,
                                         float a4, float a5, float a6, float a7) {
  u32 A = pk_bf16(a0, a1), B = pk_bf16(a2, a3);
  u32 C = pk_bf16(a4, a5), D = pk_bf16(a6, a7);
  asm volatile("v_permlane32_swap_b32 %0, %1" : "+v"(A), "+v"(C));
  asm volatile("v_permlane32_swap_b32 %0, %1" : "+v"(B), "+v"(D));
  union { u32 w[4]; bf16x8 v; } u;
  u.w[0] = A; u.w[1] = B; u.w[2] = C; u.w[3] = D;
  return u.v;
}

// ---------------- all-weights fp32 -> bf16 (one launch) ----------------
__global__ void k_cvt_all(const float* __restrict__ Wt, const float* __restrict__ Wp,
                          const float* __restrict__ Wg, const float* __restrict__ Wo,
                          u16* __restrict__ dst) {
  int i = (blockIdx.x * 256 + threadIdx.x) * 4;
  const float* s; int off;
  if (i < 32768)       { s = Wt; off = i; }
  else if (i < 98304)  { s = Wp; off = i - 32768; }
  else if (i < 163840) { s = Wg; off = i - 98304; }
  else                 { s = Wo; off = i - 163840; }
  float4 v = *(const float4*)(s + off);
  *(uint2*)(dst + i) = make_uint2(pk_bf16(v.x, v.y), pk_bf16(v.z, v.w));
}

// ---------------- theta projection -> pixel-major [B][p][c'] ----------------
__global__ void k_proj_pix(const float* __restrict__ X, const u16* __restrict__ W,
                           const float* __restrict__ bias, u16* __restrict__ O,
                           int Cin, float scale) {
  const int b = blockIdx.y, p0 = blockIdx.x * 64;
  const int t = threadIdx.x, lane = t & 63, w = t >> 6;
  const int m_ = lane & 15, h = lane >> 4;
  __shared__ __align__(16) u16 At[64][40];
  __shared__ __align__(16) u16 Wl[128][40];
  const float* xb = X + (size_t)b * Cin * PTOT;
  f32x4 acc[4][2];
#pragma unroll
  for (int i = 0; i < 4; i++) { acc[i][0] = (f32x4)0.0f; acc[i][1] = (f32x4)0.0f; }
  const int p = t & 63, cg = t >> 6;
  const int wrow = t >> 1, whalf = t & 1;
  for (int k0 = 0; k0 < Cin; k0 += 32) {
    __syncthreads();
    {
      const float* sx = xb + (size_t)(k0 + 8 * cg) * PTOT + p0 + p;
      float v0 = sx[0],        v1 = sx[PTOT],   v2 = sx[2*PTOT], v3 = sx[3*PTOT];
      float v4 = sx[4*PTOT],   v5 = sx[5*PTOT], v6 = sx[6*PTOT], v7 = sx[7*PTOT];
      *(uint2*)&At[p][8*cg]     = make_uint2(pk_bf16(v0,v1), pk_bf16(v2,v3));
      *(uint2*)&At[p][8*cg + 4] = make_uint2(pk_bf16(v4,v5), pk_bf16(v6,v7));
    }
    {
      const u16* sw = W + (size_t)wrow * Cin + k0 + whalf * 16;
      uint4 a = *(const uint4*)sw, c = *(const uint4*)(sw + 8);
      *(uint4*)&Wl[wrow][whalf*16]     = a;
      *(uint4*)&Wl[wrow][whalf*16 + 8] = c;
    }
    __syncthreads();
    bf16x8 bf0 = *(const bf16x8*)&Wl[w*32 + m_][8*h];
    bf16x8 bf1 = *(const bf16x8*)&Wl[w*32 + 16 + m_][8*h];
#pragma unroll
    for (int mb = 0; mb < 4; mb++) {
      bf16x8 af = *(const bf16x8*)&At[mb*16 + m_][8*h];
      acc[mb][0] = mfma16(af, bf0, acc[mb][0]);
      acc[mb][1] = mfma16(af, bf1, acc[mb][1]);
    }
  }
  u16* ob = O + (size_t)b * PTOT * CINT;
#pragma unroll
  for (int mb = 0; mb < 4; mb++)
#pragma unroll
    for (int nb = 0; nb < 2; nb++) {
      int c = w*32 + nb*16 + m_;
      float bv = bias[c];
#pragma unroll
      for (int r = 0; r < 4; r++) {
        int pp = p0 + mb*16 + 4*h + r;
        ob[(size_t)pp * CINT + c] = f2bf((acc[mb][nb][r] + bv) * scale);
      }
    }
}

// ---------------- fused reference projections: phi (pixel-major) + g (channel-major) ----------------
__global__ void k_proj_ref(const float* __restrict__ X, const u16* __restrict__ Wp,
                           const u16* __restrict__ Wg, const float* __restrict__ bp,
                           const float* __restrict__ bg, u16* __restrict__ PH,
                           u16* __restrict__ Gm) {
  const int Cin = 512;
  const int b = blockIdx.y, p0 = blockIdx.x * 64;
  const int t = threadIdx.x, lane = t & 63, w = t >> 6;
  const int m_ = lane & 15, h = lane >> 4;
  __shared__ __align__(16) u16 Bt[64][40];
  __shared__ __align__(16) u16 Wpl[128][40];
  __shared__ __align__(16) u16 Wgl[128][40];
  const float* xb = X + (size_t)b * Cin * PTOT;
  f32x4 accp[4][2];  // PH: rows p, cols c'
  f32x4 accg[2][4];  // G : rows c', cols p
#pragma unroll
  for (int i = 0; i < 4; i++) { accp[i][0] = (f32x4)0.0f; accp[i][1] = (f32x4)0.0f; }
#pragma unroll
  for (int i = 0; i < 2; i++)
#pragma unroll
    for (int j = 0; j < 4; j++) accg[i][j] = (f32x4)0.0f;
  const int p = t & 63, cg = t >> 6;
  const int wrow = t >> 1, whalf = t & 1;
  for (int k0 = 0; k0 < Cin; k0 += 32) {
    __syncthreads();
    {
      const float* sx = xb + (size_t)(k0 + 8 * cg) * PTOT + p0 + p;
      float v0 = sx[0],        v1 = sx[PTOT],   v2 = sx[2*PTOT], v3 = sx[3*PTOT];
      float v4 = sx[4*PTOT],   v5 = sx[5*PTOT], v6 = sx[6*PTOT], v7 = sx[7*PTOT];
      *(uint2*)&Bt[p][8*cg]     = make_uint2(pk_bf16(v0,v1), pk_bf16(v2,v3));
      *(uint2*)&Bt[p][8*cg + 4] = make_uint2(pk_bf16(v4,v5), pk_bf16(v6,v7));
    }
    {
      const u16* sw = Wp + (size_t)wrow * Cin + k0 + whalf * 16;
      *(uint4*)&Wpl[wrow][whalf*16]     = *(const uint4*)sw;
      *(uint4*)&Wpl[wrow][whalf*16 + 8] = *(const uint4*)(sw + 8);
      const u16* sg = Wg + (size_t)wrow * Cin + k0 + whalf * 16;
      *(uint4*)&Wgl[wrow][whalf*16]     = *(const uint4*)sg;
      *(uint4*)&Wgl[wrow][whalf*16 + 8] = *(const uint4*)(sg + 8);
    }
    __syncthreads();
    {
      bf16x8 bf0 = *(const bf16x8*)&Wpl[w*32 + m_][8*h];
      bf16x8 bf1 = *(const bf16x8*)&Wpl[w*32 + 16 + m_][8*h];
#pragma unroll
      for (int mb = 0; mb < 4; mb++) {
        bf16x8 af = *(const bf16x8*)&Bt[mb*16 + m_][8*h];
        accp[mb][0] = mfma16(af, bf0, accp[mb][0]);
        accp[mb][1] = mfma16(af, bf1, accp[mb][1]);
      }
    }
    {
      bf16x8 bfr[4];
#pragma unroll
      for (int nb = 0; nb < 4; nb++) bfr[nb] = *(const bf16x8*)&Bt[nb*16 + m_][8*h];
#pragma unroll
      for (int mb = 0; mb < 2; mb++) {
        bf16x8 af = *(const bf16x8*)&Wgl[w*32 + mb*16 + m_][8*h];
#pragma unroll
        for (int nb = 0; nb < 4; nb++) accg[mb][nb] = mfma16(af, bfr[nb], accg[mb][nb]);
      }
    }
  }
  {
    u16* ob = PH + (size_t)b * PTOT * CINT;
#pragma unroll
    for (int mb = 0; mb < 4; mb++)
#pragma unroll
      for (int nb = 0; nb < 2; nb++) {
        int c = w*32 + nb*16 + m_;
        float bv = bp[c];
#pragma unroll
        for (int r = 0; r < 4; r++) {
          int pp = p0 + mb*16 + 4*h + r;
          ob[(size_t)pp * CINT + c] = f2bf(accp[mb][nb][r] + bv);
        }
      }
  }
  {
    u16* ob = Gm + (size_t)b * CINT * PTOT;
#pragma unroll
    for (int mb = 0; mb < 2; mb++)
#pragma unroll
      for (int nb = 0; nb < 4; nb++) {
        int pidx = p0 + nb*16 + m_;
#pragma unroll
        for (int r = 0; r < 4; r++) {
          int c = w*32 + mb*16 + 4*h + r;
          ob[(size_t)c * PTOT + pidx] = f2bf(accg[mb][nb][r] + bg[c]);
        }
      }
  }
}

// ---------------- flash attention, 32x32 MFMA, gload_lds dbuf + counted vmcnt ----------------
// Per block: 128 q (4 waves x 32 q), KVBLK=64. K tile [64k][128c] (from PH, pixel-major),
// V tile [128c'][64k] (from G, channel-major), both XOR-swizzled, double-buffered (64 KiB).
// P stays in registers (cvt_pk + permlane32_swap -> A-operand fragments).
template<int SPLIT>
__global__ __launch_bounds__(256, 2)
void k_attn(const u16* __restrict__ TH, const u16* __restrict__ PH,
            const u16* __restrict__ G, u16* __restrict__ U,
            float* __restrict__ ML, u16* __restrict__ Y) {
  constexpr int LSPLIT = (SPLIT == 4) ? 2 : ((SPLIT == 2) ? 1 : 0);
  constexpr int NITER = 64 >> LSPLIT;
  const int total = 32 * BATCH * SPLIT;
  const int did = blockIdx.x;
  const int gid = (did & 7) * (total >> 3) + (did >> 3);   // XCD-contiguous
  const int qb = gid & 31, grp = gid >> 5;
  const int z = grp & (SPLIT - 1), b = grp >> LSPLIT;
  const int t = threadIdx.x, lane = t & 63, w = t >> 6;
  const int l31 = lane & 31, hi = lane >> 5;
  __shared__ __align__(16) u16 Kl[2][64 * 128];
  __shared__ __align__(16) u16 Vl[2][128 * 64];
  const u16* thb = TH + (size_t)b * PTOT * CINT;
  const u16* phb = PH + (size_t)b * PTOT * CINT;
  const u16* gb  = G  + (size_t)b * CINT * PTOT;
  const int q0 = qb * 128, qw = q0 + w * 32;
  // Q fragments (B-operand): lane holds Q[q=qw+l31][c = cs*16 + hi*8 + j]
  bf16x8 qf[8];
  {
    const u16* qr = thb + (size_t)(qw + l31) * CINT + hi * 8;
#pragma unroll
    for (int cs = 0; cs < 8; cs++) qf[cs] = *(const bf16x8*)(qr + cs * 16);
  }
  f32x16 yacc[4];
#pragma unroll
  for (int i = 0; i < 4; i++) yacc[i] = (f32x16)0.0f;
  float mrun = -3.0e38f, lrun = 0.0f;
  const int it0 = z * NITER;

  auto STAGE = [&](int bb, int it) {
    const int k0 = it * 64;
#pragma unroll
    for (int i = 0; i < 4; i++) {
      const int s = w * 4 + i;
      {  // K seg: 4 rows x 128 u16, linear LDS dest, inverse-swizzled global source
        const int row = s * 4 + (lane >> 4);
        const int x = ((lane & 15) * 8) ^ ((row & 7) << 3);
        gload16(phb + (size_t)(k0 + row) * CINT + x, &Kl[bb][s * 512]);
      }
      {  // V seg: 8 rows x 64 u16
        const int row = s * 8 + (lane >> 3);
        const int x = ((lane & 7) * 8) ^ ((row & 7) << 3);
        gload16(gb + (size_t)row * PTOT + k0 + x, &Vl[bb][s * 512]);
      }
    }
  };

  int cur = 0;
  STAGE(0, it0);   // 8 gload_lds in flight
  for (int it = it0; it < it0 + NITER; ++it) {
    __builtin_amdgcn_s_barrier();          // all waves done reading buf[cur^1]
    if (it + 1 < it0 + NITER) {
      STAGE(cur ^ 1, it + 1);              // 8 more in flight
      asm volatile("s_waitcnt vmcnt(8)" ::: "memory");   // buf[cur] complete
    } else {
      asm volatile("s_waitcnt vmcnt(0)" ::: "memory");
    }
    __builtin_amdgcn_s_barrier();          // buf[cur] visible to all waves
    __builtin_amdgcn_sched_barrier(0);
    // ---- QK: S^T[k][q], A = K rows, B = Q ----
    f32x16 sa0 = (f32x16)0.0f, sa1 = (f32x16)0.0f;
    __builtin_amdgcn_s_setprio(1);
#pragma unroll
    for (int cs = 0; cs < 8; cs++) {
      const int xc = cs * 16 + hi * 8;
      const int r0 = l31, r1 = 32 + l31;
      bf16x8 a0 = *(const bf16x8*)&Kl[cur][r0 * 128 + (xc ^ ((r0 & 7) << 3))];
      bf16x8 a1 = *(const bf16x8*)&Kl[cur][r1 * 128 + (xc ^ ((r1 & 7) << 3))];
      sa0 = mfma32(a0, qf[cs], sa0);
      sa1 = mfma32(a1, qf[cs], sa1);
    }
    __builtin_amdgcn_s_setprio(0);
    // ---- online softmax over k (lane holds 32 of 64 k for q = qw + l31) ----
    float tm = sa0[0];
#pragma unroll
    for (int i = 1; i < 16; i++) tm = fmaxf(tm, sa0[i]);
#pragma unroll
    for (int i = 0; i < 16; i++) tm = fmaxf(tm, sa1[i]);
    tm = fmaxf(tm, __shfl_xor(tm, 32));
    if (!__all(tm <= mrun + 8.0f)) {       // defer-max (T13)
      float mnew = fmaxf(mrun, tm);
      float f = exp2f(mrun - mnew);
      mrun = mnew; lrun *= f;
#pragma unroll
      for (int i = 0; i < 4; i++) yacc[i] *= f;
    }
    float e0[16], e1[16], ts = 0.0f;
#pragma unroll
    for (int i = 0; i < 16; i++) { e0[i] = exp2f(sa0[i] - mrun); ts += e0[i]; }
#pragma unroll
    for (int i = 0; i < 16; i++) { e1[i] = exp2f(sa1[i] - mrun); ts += e1[i]; }
    ts += __shfl_xor(ts, 32);
    lrun += ts;
    // ---- P fragments in registers (T12) ----
    bf16x8 pa[4];
    pa[0] = mkfrag(e0[0], e0[1], e0[2], e0[3], e0[4], e0[5], e0[6], e0[7]);
    pa[1] = mkfrag(e0[8], e0[9], e0[10], e0[11], e0[12], e0[13], e0[14], e0[15]);
    pa[2] = mkfrag(e1[0], e1[1], e1[2], e1[3], e1[4], e1[5], e1[6], e1[7]);
    pa[3] = mkfrag(e1[8], e1[9], e1[10], e1[11], e1[12], e1[13], e1[14], e1[15]);
    // ---- PV: y[q][c'] += P[q][k] * V[k][c'] ----
    __builtin_amdgcn_s_setprio(1);
#pragma unroll
    for (int fs = 0; fs < 4; fs++) {
      const int xk = fs * 16 + hi * 8;
#pragma unroll
      for (int nt = 0; nt < 4; nt++) {
        const int r = nt * 32 + l31;
        bf16x8 vf = *(const bf16x8*)&Vl[cur][r * 64 + (xk ^ ((r & 7) << 3))];
        yacc[nt] = mfma32(pa[fs], vf, yacc[nt]);
      }
    }
    __builtin_amdgcn_s_setprio(0);
    cur ^= 1;
  }
  // ---- epilogue ----
  if constexpr (SPLIT > 1) {
    u16* ub = U + (size_t)(z * BATCH + b) * PTOT * CINT;
#pragma unroll
    for (int reg = 0; reg < 16; reg++) {
      const int qq = qw + (reg & 3) + 8 * (reg >> 2) + 4 * hi;
      u16* row = ub + (size_t)qq * CINT + l31;
      row[0]  = f2bf(yacc[0][reg]);
      row[32] = f2bf(yacc[1][reg]);
      row[64] = f2bf(yacc[2][reg]);
      row[96] = f2bf(yacc[3][reg]);
    }
    if (lane < 32) {
      float* mlb = ML + ((size_t)(z * BATCH + b) * PTOT + qw + lane) * 2;
      mlb[0] = mrun; mlb[1] = lrun;
    }
  } else {
    const float inv = 1.0f / lrun;
    u16* yb = Y + (size_t)b * PTOT * CINT;
#pragma unroll
    for (int reg = 0; reg < 16; reg++) {
      const int qq = qw + (reg & 3) + 8 * (reg >> 2) + 4 * hi;
      u16* row = yb + (size_t)qq * CINT + l31;
      row[0]  = f2bf(yacc[0][reg] * inv);
      row[32] = f2bf(yacc[1][reg] * inv);
      row[64] = f2bf(yacc[2][reg] * inv);
      row[96] = f2bf(yacc[3][reg] * inv);
    }
  }
}

// ---------------- combine SPLIT partials ----------------
template<int SPLIT>
__global__ void k_combine(const u16* __restrict__ U, const float* __restrict__ ML,
                          u16* __restrict__ Y) {
  int tid = blockIdx.x * 256 + threadIdx.x;     // 4*4096*16 threads
  int c8 = (tid & 15) * 8;
  int q  = (tid >> 4) & (PTOT - 1);
  int b  = tid >> 16;
  float ms[SPLIT], ls[SPLIT];
  float M = -3.0e38f;
#pragma unroll
  for (int s = 0; s < SPLIT; s++) {
    const float* p = ML + ((size_t)(s * BATCH + b) * PTOT + q) * 2;
    ms[s] = p[0]; ls[s] = p[1];
    M = fmaxf(M, ms[s]);
  }
  float L = 0.0f;
#pragma unroll
  for (int s = 0; s < SPLIT; s++) { ms[s] = exp2f(ms[s] - M); L += ls[s] * ms[s]; }
  float inv = 1.0f / L;
  float acc[8];
#pragma unroll
  for (int j = 0; j < 8; j++) acc[j] = 0.0f;
#pragma unroll
  for (int s = 0; s < SPLIT; s++) {
    const u16* up = U + ((size_t)(s * BATCH + b) * PTOT + q) * CINT + c8;
    uint4 v = *(const uint4*)up;
    float f = ms[s];
    acc[0] += bf2f((u16)(v.x & 0xffff)) * f;  acc[1] += bf2f((u16)(v.x >> 16)) * f;
    acc[2] += bf2f((u16)(v.y & 0xffff)) * f;  acc[3] += bf2f((u16)(v.y >> 16)) * f;
    acc[4] += bf2f((u16)(v.z & 0xffff)) * f;  acc[5] += bf2f((u16)(v.z >> 16)) * f;
    acc[6] += bf2f((u16)(v.w & 0xffff)) * f;  acc[7] += bf2f((u16)(v.w >> 16)) * f;
  }
  uint4 o;
  o.x = pk_bf16(acc[0] * inv, acc[1] * inv);
  o.y = pk_bf16(acc[2] * inv, acc[3] * inv);
  o.z = pk_bf16(acc[4] * inv, acc[5] * inv);
  o.w = pk_bf16(acc[6] * inv, acc[7] * inv);
  *(uint4*)(Y + ((size_t)b * PTOT + q) * CINT + c8) = o;
}

// ---------------- output projection + residual ----------------
__global__ void k_outproj(const float* __restrict__ Q, const u16* __restrict__ Wo,
                          const float* __restrict__ bo, const u16* __restrict__ Y,
                          float* __restrict__ O) {
  const int p0 = blockIdx.x * 64, chh = blockIdx.y, b = blockIdx.z;
  const int t = threadIdx.x, lane = t & 63, w = t >> 6;
  const int m_ = lane & 15, h = lane >> 4;
  __shared__ __align__(16) u16 Wl[128][136];
  __shared__ __align__(16) u16 Yl[64][136];
  {
    int row = t >> 1, cc = t & 1;
    const u16* src = Wo + (size_t)(chh*128 + row) * CINT + cc*64;
#pragma unroll
    for (int i = 0; i < 8; i++)
      *(uint4*)&Wl[row][cc*64 + i*8] = *(const uint4*)(src + i*8);
  }
  {
    int row = t >> 2, cc = t & 3;
    const u16* src = Y + ((size_t)b * PTOT + p0 + row) * CINT + cc*32;
#pragma unroll
    for (int i = 0; i < 4; i++)
      *(uint4*)&Yl[row][cc*32 + i*8] = *(const uint4*)(src + i*8);
  }
  __syncthreads();
  f32x4 acc[2][4];
#pragma unroll
  for (int i = 0; i < 2; i++)
#pragma unroll
    for (int j = 0; j < 4; j++) acc[i][j] = (f32x4)0.0f;
#pragma unroll
  for (int ks = 0; ks < 4; ks++) {
    bf16x8 bfr[4];
#pragma unroll
    for (int nb = 0; nb < 4; nb++) bfr[nb] = *(const bf16x8*)&Yl[nb*16 + m_][ks*32 + 8*h];
#pragma unroll
    for (int mb = 0; mb < 2; mb++) {
      bf16x8 af = *(const bf16x8*)&Wl[w*32 + mb*16 + m_][ks*32 + 8*h];
#pragma unroll
      for (int nb = 0; nb < 4; nb++) acc[mb][nb] = mfma16(af, bfr[nb], acc[mb][nb]);
    }
  }
  const size_t cob = (size_t)b * 256 + (size_t)chh * 128;
#pragma unroll
  for (int mb = 0; mb < 2; mb++)
#pragma unroll
    for (int nb = 0; nb < 4; nb++) {
      int pidx = p0 + nb*16 + m_;
#pragma unroll
      for (int r = 0; r < 4; r++) {
        int co = w*32 + mb*16 + 4*h + r;
        size_t idx = (cob + co) * PTOT + pidx;
        O[idx] = Q[idx] + acc[mb][nb][r] + bo[chh*128 + co];
      }
    }
}

extern "C" void kernel_launch(void* const* d_in, const int* in_sizes, int n_in,
                              void* d_out, int out_size, void* d_ws, size_t ws_size,
                              hipStream_t stream) {
  const float* q_in = (const float*)d_in[0];
  const float* ref  = (const float*)d_in[1];
  const float* Wg   = (const float*)d_in[2];
  const float* bg   = (const float*)d_in[3];
  const float* Wt   = (const float*)d_in[4];
  const float* bt   = (const float*)d_in[5];
  const float* Wp   = (const float*)d_in[6];
  const float* bp   = (const float*)d_in[7];
  const float* Wo   = (const float*)d_in[8];
  const float* bo   = (const float*)d_in[9];
  float* out = (float*)d_out;
  char* ws = (char*)d_ws;

  // workspace layout (bytes)
  u16* WB  = (u16*)ws;               // weights bf16: Wt@0 Wp@32768 Wg@98304 Wo@163840 (u16 elems)
  u16* WtB = WB;
  u16* WpB = WB + 32768;
  u16* WgB = WB + 98304;
  u16* WoB = WB + 163840;
  u16* TH  = (u16*)(ws + 393216);    // 4 MiB
  u16* PH  = (u16*)(ws + 4587520);   // 4 MiB
  u16* G   = (u16*)(ws + 8781824);   // 4 MiB
  u16* U   = (u16*)(ws + 12976128);  // SPLIT * 4 MiB (bf16 partials)
  const size_t NEED4 = 12976128 + 16777216 + 524288;  // 30,277,632
  const size_t NEED2 = 12976128 +  8388608 + 262144;  // 21,626,880
  int split = (ws_size >= NEED4) ? 4 : (ws_size >= NEED2) ? 2 : 1;
  float* ML = (float*)(ws + 12976128 + (size_t)split * 4194304);
  u16* Y = (split > 1) ? TH : (u16*)(ws + 12976128);

  k_cvt_all<<<192, 256, 0, stream>>>(Wt, Wp, Wg, Wo, WB);

  dim3 gp(64, BATCH);
  k_proj_pix<<<gp, 256, 0, stream>>>(q_in, WtB, bt, TH, 256, QK_SCALE);
  k_proj_ref<<<gp, 256, 0, stream>>>(ref, WpB, WgB, bp, bg, PH, G);

  if (split == 4) {
    k_attn<4><<<512, 256, 0, stream>>>(TH, PH, G, U, ML, Y);
    k_combine<4><<<1024, 256, 0, stream>>>(U, ML, Y);
  } else if (split == 2) {
    k_attn<2><<<256, 256, 0, stream>>>(TH, PH, G, U, ML, Y);
    k_combine<2><<<1024, 256, 0, stream>>>(U, ML, Y);
  } else {
    k_attn<1><<<128, 256, 0, stream>>>(TH, PH, G, U, ML, Y);
  }

  dim3 go(64, 2, BATCH);
  k_outproj<<<go, 256, 0, stream>>>(q_in, WoB, bo, Y, out);
}